// Round 1
// baseline (195.253 us; speedup 1.0000x reference)
//
#include <hip/hip_runtime.h>

#define H 224
#define W 224
#define HW (224 * 224)
#define CIN 3
#define OCH 64

// ---------------- Kernel A: Gaussian FOA modulation ----------------
// Per pixel: sigma = 0.01 + 0.99 * dist(FOA)/sqrt(H^2+W^2)
// kern(ki,kj) ∝ e1^((ki-3)^2) * e1^((kj-3)^2), e1 = exp(-1/(2 sigma^2))
// Separable per-pixel: 7 row sums then combine; normalize by (sum px)^2.
__global__ __launch_bounds__(256) void modulate_kernel(
    const float* __restrict__ in, const int* __restrict__ foa,
    float* __restrict__ outm)
{
    int idx = blockIdx.x * 256 + threadIdx.x;
    int b = blockIdx.y;
    if (idx >= HW) return;
    int r = idx / W;
    int c = idx - r * W;

    const float* x = in + (size_t)b * CIN * HW;

    float fr = (float)foa[2 * b + 0];
    float fc = (float)foa[2 * b + 1];
    float dr = (float)r - fr, dc = (float)c - fc;
    float dist = sqrtf(dr * dr + dc * dc) * 3.1567268e-3f; // 1/sqrt(224^2+224^2)
    float sigma = 0.01f + 0.99f * dist;
    float ae = -0.5f / (sigma * sigma);
    float e1 = __expf(ae);
    float e2 = e1 * e1;
    float e4 = e2 * e2;
    float e9 = e4 * e4 * e1;
    float px[7] = {e9, e4, e1, 1.0f, e1, e4, e9};
    float S = 1.0f + 2.0f * (e1 + e4 + e9);
    float inv = 1.0f / (S * S);

    float a0 = 0.f, a1 = 0.f, a2 = 0.f;
    #pragma unroll
    for (int ki = 0; ki < 7; ++ki) {
        int rr = r + ki - 3;
        if (rr < 0 || rr >= H) continue;
        const float* row = x + rr * W;
        float r0 = 0.f, r1 = 0.f, r2 = 0.f;
        #pragma unroll
        for (int kj = 0; kj < 7; ++kj) {
            int cc = c + kj - 3;
            if (cc < 0 || cc >= W) continue;
            float w = px[kj];
            r0 += w * row[cc];
            r1 += w * row[HW + cc];
            r2 += w * row[2 * HW + cc];
        }
        float wk = px[ki];
        a0 += wk * r0;
        a1 += wk * r1;
        a2 += wk * r2;
    }
    float* o = outm + (size_t)b * CIN * HW + idx;
    o[0]      = a0 * inv;
    o[HW]     = a1 * inv;
    o[2 * HW] = a2 * inv;
}

// ---------------- Kernel B: 5x5 conv, 3 -> 64 channels ----------------
// Block: 256 threads; spatial tile 64(w) x 16(h); 8 output channels/block.
// Thread: 4-wide pixel strip x 8 oc = 32 accumulators.
// Input tile in LDS (aligned rows for ds_read_b128); weights read with
// block-uniform addresses (expect s_load scalarization).
#define TH 16
#define TW 64
#define SROW 72  // row stride in floats: >=68, multiple of 4 (16B aligned)

__global__ __launch_bounds__(256) void conv_kernel(
    const float* __restrict__ mod, const float* __restrict__ wgt,
    float* __restrict__ out)
{
    __shared__ __align__(16) float s_in[CIN][TH + 4][SROW];

    int tile = blockIdx.x;           // 0..55 : 4 x-tiles * 14 y-tiles
    int ocg  = blockIdx.y;           // 0..7  : group of 8 output channels
    int b    = blockIdx.z;           // batch
    int tx0 = (tile & 3) * TW;
    int ty0 = (tile >> 2) * TH;
    int tid = threadIdx.x;

    // ---- stage input tile (with 2-halo) into LDS, zeros outside image ----
    const float* src = mod + (size_t)b * CIN * HW;
    for (int i = tid; i < CIN * (TH + 4) * 68; i += 256) {
        int ch  = i / ((TH + 4) * 68);
        int rem = i - ch * ((TH + 4) * 68);
        int lr  = rem / 68;
        int lc  = rem - lr * 68;
        int gr = ty0 - 2 + lr;
        int gc = tx0 - 2 + lc;
        float v = 0.f;
        if (gr >= 0 && gr < H && gc >= 0 && gc < W)
            v = src[ch * HW + gr * W + gc];
        s_in[ch][lr][lc] = v;
    }
    __syncthreads();

    int strip = tid & 15;   // 16 strips of 4 pixels across the 64-wide tile
    int ry    = tid >> 4;   // 0..15 row within tile
    int rx0   = strip << 2;

    float acc[8][4];
    #pragma unroll
    for (int i = 0; i < 8; ++i)
        #pragma unroll
        for (int j = 0; j < 4; ++j) acc[i][j] = 0.f;

    const float* wbase = wgt + (size_t)(ocg * 8) * (CIN * 25);

    #pragma unroll
    for (int ch = 0; ch < CIN; ++ch) {
        #pragma unroll
        for (int ky = 0; ky < 5; ++ky) {
            const float* rp = &s_in[ch][ry + ky][rx0];
            float4 va = *(const float4*)rp;
            float4 vb = *(const float4*)(rp + 4);
            float v[8] = {va.x, va.y, va.z, va.w, vb.x, vb.y, vb.z, vb.w};
            #pragma unroll
            for (int kx = 0; kx < 5; ++kx) {
                #pragma unroll
                for (int oc = 0; oc < 8; ++oc) {
                    float wv = wbase[(oc * CIN + ch) * 25 + ky * 5 + kx];
                    #pragma unroll
                    for (int p = 0; p < 4; ++p)
                        acc[oc][p] += wv * v[kx + p];
                }
            }
        }
    }

    // ---- store: x strips are 4-aligned and 224 % 4 == 0, so strips are
    // either fully in-bounds or fully out (only the 4th x-tile is partial) ----
    int gx = tx0 + rx0;
    int gy = ty0 + ry;
    if (gx < W) {
        float* op = out + ((((size_t)b * OCH + ocg * 8) * H + gy) * W) + gx;
        #pragma unroll
        for (int oc = 0; oc < 8; ++oc) {
            float4 v4 = make_float4(acc[oc][0], acc[oc][1], acc[oc][2], acc[oc][3]);
            *(float4*)(op + (size_t)oc * HW) = v4;
        }
    }
}

extern "C" void kernel_launch(void* const* d_in, const int* in_sizes, int n_in,
                              void* d_out, int out_size, void* d_ws, size_t ws_size,
                              hipStream_t stream) {
    const float* input  = (const float*)d_in[0];   // (8,3,224,224) fp32
    const int*   foa    = (const int*)d_in[1];     // (8,2) int32
    const float* weight = (const float*)d_in[2];   // (64,3,5,5) fp32
    float* outp = (float*)d_out;                   // (8,64,224,224) fp32
    float* modbuf = (float*)d_ws;                  // 8*3*224*224 floats = 4.6 MB

    dim3 gridA((HW + 255) / 256, 8);
    modulate_kernel<<<gridA, 256, 0, stream>>>(input, foa, modbuf);

    dim3 gridB(4 * 14, 8, 8);   // x/y tiles, oc groups, batch
    conv_kernel<<<gridB, 256, 0, stream>>>(modbuf, weight, outp);
}

// Round 2
// 161.675 us; speedup vs baseline: 1.2077x; 1.2077x over previous
//
#include <hip/hip_runtime.h>

#define H 224
#define W 224
#define HW (224 * 224)
#define CIN 3
#define OCH 64
#define KG 7          // gaussian kernel
#define KC 5          // conv kernel
#define TLW 32        // tile width  (224/32 = 7 exact)
#define TLH 8         // tile height (224/8 = 28 exact)
// raw tile: (TLH+4+6) x (TLW+4+6) = 18 x 42, rows padded to 44
// mod tile: (TLH+4)   x (TLW+4)   = 12 x 36, rows padded to 40

// ---- tiny pre-pass: transpose weights (64,3,5,5) -> wT[75][64] so the 64
// per-k weights are contiguous (enables s_load_dwordx16 scalarization) ----
__global__ void transpose_w(const float* __restrict__ w, float* __restrict__ wT) {
    int i = blockIdx.x * 256 + threadIdx.x;
    if (i < OCH * CIN * KC * KC) {
        int oc = i / 75;
        int k = i - oc * 75;
        wT[k * OCH + oc] = w[i];
    }
}

__global__ __launch_bounds__(256) void fused_kernel(
    const float* __restrict__ in, const int* __restrict__ foa,
    const float* __restrict__ wT, float* __restrict__ out)
{
    __shared__ float s_raw[CIN][18][44];
    __shared__ float s_mod[CIN][12][40];

    int tx0 = blockIdx.x * TLW;
    int ty0 = blockIdx.y * TLH;
    int b   = blockIdx.z;
    int tid = threadIdx.x;

    const float* src = in + (size_t)b * CIN * HW;

    // ---- phase 0: stage raw input tile (zero-padded outside image) ----
    for (int i = tid; i < CIN * 18 * 42; i += 256) {
        int ch  = i / (18 * 42);
        int rem = i - ch * (18 * 42);
        int rr  = rem / 42;
        int cc  = rem - rr * 42;
        int gr = ty0 - 5 + rr;
        int gc = tx0 - 5 + cc;
        float v = 0.f;
        if ((unsigned)gr < H && (unsigned)gc < W)
            v = src[ch * HW + gr * W + gc];
        s_raw[ch][rr][cc] = v;
    }
    __syncthreads();

    // ---- phase 1: per-pixel Gaussian modulation of the 12x36 halo tile ----
    float fr = (float)foa[2 * b + 0];
    float fc = (float)foa[2 * b + 1];
    for (int p = tid; p < 12 * 36; p += 256) {
        int mr = p / 36;
        int mc = p - mr * 36;
        int gr = ty0 - 2 + mr;
        int gc = tx0 - 2 + mc;
        bool inimg = ((unsigned)gr < H) && ((unsigned)gc < W);

        float dr = (float)gr - fr, dc = (float)gc - fc;
        float dist = sqrtf(dr * dr + dc * dc) * 3.1567268e-3f; // 1/sqrt(224^2+224^2)
        float sigma = 0.01f + 0.99f * dist;
        float ae = -0.5f / (sigma * sigma);
        float e1 = __expf(ae);
        float e2 = e1 * e1;
        float e4 = e2 * e2;
        float e9 = e4 * e4 * e1;
        float pw[7] = {e9, e4, e1, 1.0f, e1, e4, e9};
        float S = 1.0f + 2.0f * (e1 + e4 + e9);
        float inv = 1.0f / (S * S);

        #pragma unroll
        for (int ch = 0; ch < CIN; ++ch) {
            float a = 0.f;
            #pragma unroll
            for (int ki = 0; ki < KG; ++ki) {
                const float* rp = &s_raw[ch][mr + ki][mc];
                float rs = 0.f;
                #pragma unroll
                for (int kj = 0; kj < KG; ++kj)
                    rs += pw[kj] * rp[kj];
                a += pw[ki] * rs;
            }
            s_mod[ch][mr][mc] = inimg ? a * inv : 0.f;
        }
    }
    __syncthreads();

    // ---- phase 2: 5x5 conv, all 64 output channels per thread ----
    int py  = tid >> 5;   // 0..7
    int pxl = tid & 31;   // 0..31

    float acc[OCH];
    #pragma unroll
    for (int oc = 0; oc < OCH; ++oc) acc[oc] = 0.f;

    #pragma unroll 1
    for (int cky = 0; cky < CIN * KC; ++cky) {   // (ch,ky) pairs, keep as loop for icache
        int ch = cky / 5;
        int ky = cky - ch * 5;
        const float* rp = &s_mod[ch][py + ky][pxl];
        float v[5] = {rp[0], rp[1], rp[2], rp[3], rp[4]};
        const float* wk = wT + cky * 5 * OCH;    // block-uniform -> s_load
        #pragma unroll
        for (int kx = 0; kx < KC; ++kx) {
            const float* wp = wk + kx * OCH;
            #pragma unroll
            for (int oc = 0; oc < OCH; ++oc)
                acc[oc] = fmaf(v[kx], wp[oc], acc[oc]);
        }
    }

    // ---- store: 32 consecutive lanes -> 128B contiguous per row ----
    float* op = out + (((size_t)b * OCH) * H + (ty0 + py)) * W + (tx0 + pxl);
    #pragma unroll
    for (int oc = 0; oc < OCH; ++oc)
        op[(size_t)oc * HW] = acc[oc];
}

extern "C" void kernel_launch(void* const* d_in, const int* in_sizes, int n_in,
                              void* d_out, int out_size, void* d_ws, size_t ws_size,
                              hipStream_t stream) {
    const float* input  = (const float*)d_in[0];   // (8,3,224,224) fp32
    const int*   foa    = (const int*)d_in[1];     // (8,2) int32
    const float* weight = (const float*)d_in[2];   // (64,3,5,5) fp32
    float* outp = (float*)d_out;                   // (8,64,224,224) fp32
    float* wT   = (float*)d_ws;                    // 75*64 floats = 19.2 KB

    transpose_w<<<(OCH * CIN * KC * KC + 255) / 256, 256, 0, stream>>>(weight, wT);

    dim3 grid(W / TLW, H / TLH, 8);   // 7 x 28 x 8 = 1568 blocks, exact tiling
    fused_kernel<<<grid, 256, 0, stream>>>(input, foa, wT, outp);
}